// Round 7
// baseline (117.838 us; speedup 1.0000x reference)
//
#include <hip/hip_runtime.h>
#include <math.h>

#define B_  16
#define C_  256
#define T_  4096
#define DT_ 512
#define NH_ 8
#define HD_ 32

// ---------------------------------------------------------------------------
// k_t1gate (16 blocks x 512 thr): two independent phases.
//   A: t1 = gelu(F_text@tp_w1+b1)   [block owns 16 cols, 32-way split-K]
//   G: g  = sigmoid(f_cond@gp_w+b)  [gate scalars computed redundantly]
// ---------------------------------------------------------------------------
__global__ __launch_bounds__(512) void k_t1gate(
    const float* __restrict__ F_text, const float* __restrict__ U,
    const float* __restrict__ Tt,
    const float* __restrict__ tp_w1, const float* __restrict__ tp_b1,
    const float* __restrict__ fa_w,  const float* __restrict__ fa_b,
    const float* __restrict__ gp_w,  const float* __restrict__ gp_b,
    float* __restrict__ t1, float* __restrict__ gout)
{
    __shared__ float xs[8192];
    __shared__ float part[8192];
    __shared__ float pd[2][16][32];
    __shared__ float a0s[16], a1s[16];
    int tid = threadIdx.x;
    int c0  = blockIdx.x * 16;
    int cl  = tid & 15, ks = tid >> 4;
    int c   = c0 + cl;

    // ---- Phase A: t1 (K=512, Kc=16)
    for (int idx = tid; idx < 8192; idx += 512) xs[idx] = F_text[idx];
    __syncthreads();
    {
        float acc[16];
        #pragma unroll
        for (int b = 0; b < 16; ++b) acc[b] = 0.f;
        const float* wp = tp_w1 + (size_t)(ks * 16) * 256 + c;
        #pragma unroll
        for (int i = 0; i < 16; ++i) {
            float w = wp[(size_t)i * 256];
            int xi = ks * 16 + i;
            #pragma unroll
            for (int b = 0; b < 16; ++b) acc[b] += xs[b * 512 + xi] * w;
        }
        #pragma unroll
        for (int b = 0; b < 16; ++b) part[ks * 256 + b * 16 + cl] = acc[b];
    }
    __syncthreads();
    if (tid < 256) {
        int b = tid >> 4, cc = tid & 15;
        float s = 0.f;
        #pragma unroll
        for (int k2 = 0; k2 < 32; ++k2) s += part[k2 * 256 + b * 16 + cc];
        s += tp_b1[c0 + cc];
        s = 0.5f * s * (1.0f + erff(s * 0.70710678118654752f));
        t1[b * 256 + c0 + cc] = s;
    }
    __syncthreads();

    // ---- Phase G: gate
    {
        int b = tid >> 5, sl = tid & 31;
        const float* ub = U  + b * 512 + sl * 16;
        const float* tb = Tt + b * 512 + sl * 16;
        const float* fw = fa_w + sl * 16;
        float su = 0.f, st = 0.f;
        #pragma unroll
        for (int j = 0; j < 16; ++j) { su += ub[j] * fw[j]; st += tb[j] * fw[j]; }
        pd[0][b][sl] = su; pd[1][b][sl] = st;
    }
    __syncthreads();
    if (tid < 16) {
        float s0 = fa_b[0], s1 = fa_b[0];
        #pragma unroll
        for (int sl = 0; sl < 32; ++sl) { s0 += pd[0][tid][sl]; s1 += pd[1][tid][sl]; }
        float mm = fmaxf(s0, s1);
        float e0 = expf(s0 - mm), e1 = expf(s1 - mm);
        float inv = 1.0f / (e0 + e1);
        a0s[tid] = e0 * inv; a1s[tid] = e1 * inv;
    }
    __syncthreads();
    for (int idx = tid; idx < 8192; idx += 512) {
        int b = idx >> 9;
        xs[idx] = a0s[b] * U[idx] + a1s[b] * Tt[idx];
    }
    __syncthreads();
    {
        float acc[16];
        #pragma unroll
        for (int b = 0; b < 16; ++b) acc[b] = 0.f;
        const float* wp = gp_w + (size_t)(ks * 16) * 256 + c;
        #pragma unroll
        for (int i = 0; i < 16; ++i) {
            float w = wp[(size_t)i * 256];
            int xi = ks * 16 + i;
            #pragma unroll
            for (int b = 0; b < 16; ++b) acc[b] += xs[b * 512 + xi] * w;
        }
        #pragma unroll
        for (int b = 0; b < 16; ++b) part[ks * 256 + b * 16 + cl] = acc[b];
    }
    __syncthreads();
    if (tid < 256) {
        int b = tid >> 4, cc = tid & 15;
        float s = 0.f;
        #pragma unroll
        for (int k2 = 0; k2 < 32; ++k2) s += part[k2 * 256 + b * 16 + cc];
        s += gp_b[c0 + cc];
        gout[b * 256 + c0 + cc] = 1.0f / (1.0f + expf(-s));
    }
}

// ---------------------------------------------------------------------------
// gemm16<K,ACT>: out[16][256] = act(x[16][K] @ W[K][256] + bias)  (tv step)
// ---------------------------------------------------------------------------
template<int K, int ACT>
__global__ __launch_bounds__(512) void gemm16(const float* __restrict__ x,
                                              const float* __restrict__ W,
                                              const float* __restrict__ bias,
                                              float* __restrict__ out)
{
    __shared__ float xs[16 * K];
    __shared__ float part[32 * 256];
    int tid = threadIdx.x;
    int c0  = blockIdx.x * 16;

    for (int idx = tid; idx < 16 * K; idx += 512) xs[idx] = x[idx];
    __syncthreads();

    int cl = tid & 15, ks = tid >> 4;
    const int Kc = K / 32;
    int c = c0 + cl;

    float acc[16];
    #pragma unroll
    for (int b = 0; b < 16; ++b) acc[b] = 0.f;

    const float* wp = W + (size_t)(ks * Kc) * 256 + c;
    #pragma unroll
    for (int i = 0; i < Kc; ++i) {
        float w  = wp[(size_t)i * 256];
        int   xi = ks * Kc + i;
        #pragma unroll
        for (int b = 0; b < 16; ++b) acc[b] += xs[b * K + xi] * w;
    }
    #pragma unroll
    for (int b = 0; b < 16; ++b) part[ks * 256 + b * 16 + cl] = acc[b];
    __syncthreads();

    if (tid < 256) {
        int b = tid >> 4, cc = tid & 15;
        float s = 0.f;
        #pragma unroll
        for (int k2 = 0; k2 < 32; ++k2) s += part[k2 * 256 + b * 16 + cc];
        s += bias[c0 + cc];
        if (ACT == 1) s = 0.5f * s * (1.0f + erff(s * 0.70710678118654752f));
        out[b * 256 + c0 + cc] = s;
    }
}

// ---------------------------------------------------------------------------
// k_qkq (8 blocks = 1 head each, 512 thr): q-slice + kq + qkb fused.
// ---------------------------------------------------------------------------
__global__ __launch_bounds__(512) void k_qkq(const float* __restrict__ tv,
                                             const float* __restrict__ q_w,
                                             const float* __restrict__ q_b,
                                             const float* __restrict__ k_w,
                                             const float* __restrict__ k_b,
                                             float* __restrict__ kq,
                                             float* __restrict__ qkb)
{
    __shared__ float xs[4096];          // tv [16][256]
    __shared__ float part[8192];        // [16 ks][16 b][32 cl]
    __shared__ float qs[512];           // q [16 b][32 d]
    int tid = threadIdx.x;
    int h   = blockIdx.x;

    for (int idx = tid; idx < 4096; idx += 512) xs[idx] = tv[idx];
    __syncthreads();

    {   // P1: q-slice
        int cl = tid & 31, ks = tid >> 5;
        float acc[16];
        #pragma unroll
        for (int b = 0; b < 16; ++b) acc[b] = 0.f;
        const float* wp = q_w + (size_t)(ks * 16) * 256 + h * HD_ + cl;
        #pragma unroll
        for (int i = 0; i < 16; ++i) {
            float w = wp[(size_t)i * 256];
            int xi = ks * 16 + i;
            #pragma unroll
            for (int b = 0; b < 16; ++b) acc[b] += xs[b * 256 + xi] * w;
        }
        #pragma unroll
        for (int b = 0; b < 16; ++b) part[(ks * 16 + b) * 32 + cl] = acc[b];
    }
    __syncthreads();
    {
        int b = tid >> 5, cl = tid & 31;
        float s = 0.f;
        #pragma unroll
        for (int k2 = 0; k2 < 16; ++k2) s += part[(k2 * 16 + b) * 32 + cl];
        qs[b * 32 + cl] = s + q_b[h * HD_ + cl];
    }
    __syncthreads();
    if (tid < 16) {
        float s = 0.f;
        #pragma unroll
        for (int d = 0; d < 32; ++d) s += qs[tid * 32 + d] * k_b[h * HD_ + d];
        qkb[tid * NH_ + h] = s;
    }

    {   // P2: kq
        int c = tid >> 1, bh = tid & 1;
        const float4* kwp = reinterpret_cast<const float4*>(k_w + (size_t)c * 256 + h * HD_);
        float4 kw[8];
        #pragma unroll
        for (int j = 0; j < 8; ++j) kw[j] = kwp[j];
        float acc[8] = {0,0,0,0,0,0,0,0};
        #pragma unroll
        for (int j = 0; j < 8; ++j) {
            float w0 = kw[j].x, w1 = kw[j].y, w2 = kw[j].z, w3 = kw[j].w;
            #pragma unroll
            for (int bi = 0; bi < 8; ++bi) {
                const float* qp = &qs[(bh * 8 + bi) * 32 + j * 4];
                acc[bi] += qp[0] * w0 + qp[1] * w1 + qp[2] * w2 + qp[3] * w3;
            }
        }
        #pragma unroll
        for (int bi = 0; bi < 8; ++bi)
            kq[((size_t)((bh * 8 + bi) * NH_ + h)) * C_ + c] = acc[bi];
    }
}

// ---------------------------------------------------------------------------
// K2s: full scores per 256-t chunk (all 256 c in-block, 4-wave split-K),
// chunk-local softmax: e = exp(s - m_chunk) -> ws, (m_chunk, sum_e) pairs.
// grid (16 tc, 16 b), 256 thr (wave = c-slice cs, lane = t-quad).
// ---------------------------------------------------------------------------
__global__ __launch_bounds__(256) void k2_scores(const float* __restrict__ F_vis,
                                                 const float* __restrict__ kq,
                                                 const float* __restrict__ qkb,
                                                 float* __restrict__ e,
                                                 float* __restrict__ ms)
{
    int tc = blockIdx.x;
    int b  = blockIdx.y;
    int tid = threadIdx.x;
    int t4 = tid & 63, cs = tid >> 6;
    int t0 = tc * 256;
    const float scale = 0.176776695296636893f;   // 32^-0.5

    __shared__ float kqs[256][9];
    __shared__ __align__(16) float4 part4[2048];  // [cs][h][t4]
    __shared__ float qkbs[8];
    __shared__ float redm[8][4], reds[8][4];

    for (int idx = tid; idx < 2048; idx += 256) {
        int c = idx & 255, h = idx >> 8;
        kqs[c][h] = kq[((size_t)(b * NH_ + h)) * C_ + c];
    }
    if (tid < 8) qkbs[tid] = qkb[b * NH_ + tid];
    __syncthreads();

    const float* fv = F_vis + ((size_t)b * C_) * T_ + t0 + t4 * 4;
    float4 acc[8];
    #pragma unroll
    for (int h = 0; h < 8; ++h) acc[h] = make_float4(0.f, 0.f, 0.f, 0.f);

    #pragma unroll 4
    for (int i = 0; i < 64; ++i) {
        int c = i * 4 + cs;
        float4 v = *reinterpret_cast<const float4*>(&fv[(size_t)c * T_]);
        #pragma unroll
        for (int h = 0; h < 8; ++h) {
            float w = kqs[c][h];
            acc[h].x += v.x * w; acc[h].y += v.y * w;
            acc[h].z += v.z * w; acc[h].w += v.w * w;
        }
    }
    #pragma unroll
    for (int h = 0; h < 8; ++h) part4[(cs * 8 + h) * 64 + t4] = acc[h];
    __syncthreads();

    const float* pf = reinterpret_cast<const float*>(part4);
    int t = tid;
    float sv[8];
    #pragma unroll
    for (int h = 0; h < 8; ++h) {
        float s = pf[(0 * 8 + h) * 256 + t] + pf[(1 * 8 + h) * 256 + t]
                + pf[(2 * 8 + h) * 256 + t] + pf[(3 * 8 + h) * 256 + t];
        sv[h] = (s + qkbs[h]) * scale;
    }
    int lane = tid & 63, wid = tid >> 6;
    #pragma unroll
    for (int h = 0; h < 8; ++h) {
        float mh = sv[h];
        #pragma unroll
        for (int o = 32; o; o >>= 1) mh = fmaxf(mh, __shfl_xor(mh, o));
        if (lane == 0) redm[h][wid] = mh;
    }
    __syncthreads();
    float ev[8];
    #pragma unroll
    for (int h = 0; h < 8; ++h) {
        float mh = fmaxf(fmaxf(redm[h][0], redm[h][1]), fmaxf(redm[h][2], redm[h][3]));
        ev[h] = expf(sv[h] - mh);
        e[((size_t)(b * NH_ + h)) * T_ + t0 + t] = ev[h];
    }
    #pragma unroll
    for (int h = 0; h < 8; ++h) {
        float sh = ev[h];
        #pragma unroll
        for (int o = 32; o; o >>= 1) sh += __shfl_xor(sh, o);
        if (lane == 0) reds[h][wid] = sh;
    }
    __syncthreads();
    if (tid < 8) {
        float mh = fmaxf(fmaxf(redm[tid][0], redm[tid][1]),
                         fmaxf(redm[tid][2], redm[tid][3]));
        float sum = reds[tid][0] + reds[tid][1] + reds[tid][2] + reds[tid][3];
        size_t base = (((size_t)(b * NH_ + tid)) * 16 + tc) * 2;
        ms[base]     = mh;
        ms[base + 1] = sum;
    }
}

// ---------------------------------------------------------------------------
// K4a: merge chunk (m,s) -> global (M, 1/Z) + factors (redundant per block);
// attn = e * fact (written by bx==0/wave0); xa partials over half-t (z).
// ---------------------------------------------------------------------------
__global__ __launch_bounds__(256, 2) void k4_xa(const float* __restrict__ F_vis,
                                                const float* __restrict__ e,
                                                const float* __restrict__ ms,
                                                float* __restrict__ attn,
                                                float* __restrict__ xa)
{
    int b = blockIdx.y, z = blockIdx.z;
    int tid = threadIdx.x, wid = tid >> 6, lane = tid & 63;
    int c0 = blockIdx.x * 16 + wid * 4;

    __shared__ float Ms[8], iZs[8];
    __shared__ float fact[8][16];
    if (tid < 8) {
        const float* mp = ms + ((size_t)(b * NH_ + tid)) * 32;
        float M = -1e30f;
        #pragma unroll
        for (int c2 = 0; c2 < 16; ++c2) M = fmaxf(M, mp[c2 * 2]);
        float Z = 0.f;
        #pragma unroll
        for (int c2 = 0; c2 < 16; ++c2) Z += mp[c2 * 2 + 1] * expf(mp[c2 * 2] - M);
        Ms[tid] = M; iZs[tid] = 1.0f / Z;
    }
    __syncthreads();
    if (tid < 128) {
        int h = tid >> 4, c2 = tid & 15;
        fact[h][c2] = expf(ms[((size_t)(b * NH_ + h)) * 32 + c2 * 2] - Ms[h]) * iZs[h];
    }
    __syncthreads();

    const float* fb = F_vis + (size_t)b * C_ * T_;
    const float* eb = e + (size_t)b * NH_ * T_;
    bool writer = (blockIdx.x == 0 && wid == 0);

    float4 acc[4][8];
    #pragma unroll
    for (int j = 0; j < 4; ++j)
        #pragma unroll
        for (int h = 0; h < 8; ++h) acc[j][h] = make_float4(0.f, 0.f, 0.f, 0.f);

    for (int it = 0; it < 8; ++it) {
        int t = z * 2048 + it * 256 + lane * 4;
        int ck = z * 8 + it;
        float4 av[8];
        #pragma unroll
        for (int h = 0; h < 8; ++h) {
            float4 a = *reinterpret_cast<const float4*>(&eb[(size_t)h * T_ + t]);
            float f = fact[h][ck];
            a.x *= f; a.y *= f; a.z *= f; a.w *= f;
            av[h] = a;
        }
        if (writer) {
            #pragma unroll
            for (int h = 0; h < 8; ++h)
                *reinterpret_cast<float4*>(&attn[((size_t)(b * NH_ + h)) * T_ + t]) = av[h];
        }
        #pragma unroll
        for (int j = 0; j < 4; ++j) {
            float4 f = *reinterpret_cast<const float4*>(&fb[(size_t)(c0 + j) * T_ + t]);
            #pragma unroll
            for (int h = 0; h < 8; ++h) {
                acc[j][h].x += f.x * av[h].x; acc[j][h].y += f.y * av[h].y;
                acc[j][h].z += f.z * av[h].z; acc[j][h].w += f.w * av[h].w;
            }
        }
    }
    #pragma unroll
    for (int j = 0; j < 4; ++j)
        #pragma unroll
        for (int h = 0; h < 8; ++h) {
            float v = acc[j][h].x + acc[j][h].y + acc[j][h].z + acc[j][h].w;
            #pragma unroll
            for (int o = 32; o; o >>= 1) v += __shfl_xor(v, o);
            if (lane == 0)
                xa[(((size_t)z * B_ + b) * NH_ + h) * C_ + c0 + j] = v;
        }
}

// ---------------------------------------------------------------------------
// K5: z = ((xa0+xa1) @ v_w + v_b) @ o_w + o_b;  gz = g * z
// ---------------------------------------------------------------------------
__global__ void k5_z(const float* __restrict__ xa,
                     const float* __restrict__ v_w, const float* __restrict__ v_b,
                     const float* __restrict__ o_w, const float* __restrict__ o_b,
                     const float* __restrict__ g,   float* __restrict__ gz)
{
    int b = blockIdx.x, j = threadIdx.x;
    __shared__ float zp[C_];
    int h = j >> 5;
    float s = v_b[j];
    const float* xr0 = xa + (((size_t)0 * B_ + b) * NH_ + h) * C_;
    const float* xr1 = xa + (((size_t)1 * B_ + b) * NH_ + h) * C_;
    #pragma unroll 8
    for (int c = 0; c < C_; c++) s += (xr0[c] + xr1[c]) * v_w[c * C_ + j];
    zp[j] = s;
    __syncthreads();
    float z = o_b[j];
    #pragma unroll 8
    for (int i = 0; i < C_; i++) z += zp[i] * o_w[i * C_ + j];
    gz[b * C_ + j] = g[b * C_ + j] * z;
}

// ---------------------------------------------------------------------------
// K6: fused residual+gate+LayerNorm, register-resident, shfl-reduce.
// ---------------------------------------------------------------------------
__global__ __launch_bounds__(256) void k6_ln(const float* __restrict__ F_vis,
                                             const float* __restrict__ gz,
                                             const float* __restrict__ ln_g,
                                             const float* __restrict__ ln_b,
                                             float* __restrict__ out)
{
    int b  = blockIdx.y;
    int t0 = blockIdx.x * 32;
    int tid = threadIdx.x;
    int t4 = tid & 7;
    int cb = tid >> 3;

    __shared__ float gzs[256], lgs[256], lbs[256];
    __shared__ float4 redS[4][8], redQ[4][8];
    __shared__ float4 mu4s[8], rs4s[8];

    gzs[tid] = gz[b * C_ + tid];
    lgs[tid] = ln_g[tid];
    lbs[tid] = ln_b[tid];
    __syncthreads();

    const float* fvb = F_vis + (size_t)b * C_ * T_ + t0 + t4 * 4;
    float4 v[8];
    float4 s = make_float4(0.f, 0.f, 0.f, 0.f);
    float4 q = make_float4(0.f, 0.f, 0.f, 0.f);
    #pragma unroll
    for (int k = 0; k < 8; ++k) {
        int c = cb + k * 32;
        float4 x = *reinterpret_cast<const float4*>(&fvb[(size_t)c * T_]);
        float gc = gzs[c];
        x.x += gc; x.y += gc; x.z += gc; x.w += gc;
        v[k] = x;
        s.x += x.x; s.y += x.y; s.z += x.z; s.w += x.w;
        q.x += x.x * x.x; q.y += x.y * x.y; q.z += x.z * x.z; q.w += x.w * x.w;
    }
    #pragma unroll
    for (int o = 8; o <= 32; o <<= 1) {
        s.x += __shfl_xor(s.x, o); s.y += __shfl_xor(s.y, o);
        s.z += __shfl_xor(s.z, o); s.w += __shfl_xor(s.w, o);
        q.x += __shfl_xor(q.x, o); q.y += __shfl_xor(q.y, o);
        q.z += __shfl_xor(q.z, o); q.w += __shfl_xor(q.w, o);
    }
    int wid = tid >> 6;
    if ((tid & 63) < 8) { redS[wid][t4] = s; redQ[wid][t4] = q; }
    __syncthreads();
    if (tid < 8) {
        float4 S = redS[0][tid], Q = redQ[0][tid];
        #pragma unroll
        for (int w = 1; w < 4; ++w) {
            float4 a = redS[w][tid], c2 = redQ[w][tid];
            S.x += a.x; S.y += a.y; S.z += a.z; S.w += a.w;
            Q.x += c2.x; Q.y += c2.y; Q.z += c2.z; Q.w += c2.w;
        }
        float4 mu, rs;
        mu.x = S.x * (1.0f / C_); mu.y = S.y * (1.0f / C_);
        mu.z = S.z * (1.0f / C_); mu.w = S.w * (1.0f / C_);
        rs.x = rsqrtf(fmaxf(Q.x * (1.0f / C_) - mu.x * mu.x, 0.f) + 1e-5f);
        rs.y = rsqrtf(fmaxf(Q.y * (1.0f / C_) - mu.y * mu.y, 0.f) + 1e-5f);
        rs.z = rsqrtf(fmaxf(Q.z * (1.0f / C_) - mu.z * mu.z, 0.f) + 1e-5f);
        rs.w = rsqrtf(fmaxf(Q.w * (1.0f / C_) - mu.w * mu.w, 0.f) + 1e-5f);
        mu4s[tid] = mu; rs4s[tid] = rs;
    }
    __syncthreads();
    float4 mu = mu4s[t4], rs = rs4s[t4];
    float* ob = out + (size_t)b * C_ * T_ + t0 + t4 * 4;
    #pragma unroll
    for (int k = 0; k < 8; ++k) {
        int c = cb + k * 32;
        float lg = lgs[c], lb = lbs[c];
        float4 o;
        o.x = (v[k].x - mu.x) * rs.x * lg + lb;
        o.y = (v[k].y - mu.y) * rs.y * lg + lb;
        o.z = (v[k].z - mu.z) * rs.z * lg + lb;
        o.w = (v[k].w - mu.w) * rs.w * lg + lb;
        *reinterpret_cast<float4*>(&ob[(size_t)c * T_]) = o;
    }
}

// ---------------------------------------------------------------------------
extern "C" void kernel_launch(void* const* d_in, const int* in_sizes, int n_in,
                              void* d_out, int out_size, void* d_ws, size_t ws_size,
                              hipStream_t stream)
{
    const float* F_vis     = (const float*)d_in[0];
    const float* F_text    = (const float*)d_in[1];
    const float* F_unified = (const float*)d_in[2];
    const float* F_teacher = (const float*)d_in[3];
    const float* tp_w1 = (const float*)d_in[4];
    const float* tp_b1 = (const float*)d_in[5];
    const float* tp_w2 = (const float*)d_in[6];
    const float* tp_b2 = (const float*)d_in[7];
    const float* q_w   = (const float*)d_in[8];
    const float* q_b   = (const float*)d_in[9];
    const float* k_w   = (const float*)d_in[10];
    const float* k_b   = (const float*)d_in[11];
    const float* v_w   = (const float*)d_in[12];
    const float* v_b   = (const float*)d_in[13];
    const float* o_w   = (const float*)d_in[14];
    const float* o_b   = (const float*)d_in[15];
    const float* fa_w  = (const float*)d_in[16];
    const float* fa_b  = (const float*)d_in[17];
    const float* gp_w  = (const float*)d_in[18];
    const float* gp_b  = (const float*)d_in[19];
    const float* ln_g  = (const float*)d_in[20];
    const float* ln_b  = (const float*)d_in[21];

    float* ws  = (float*)d_ws;
    float* t1  = ws;                    // 4096
    float* tv  = ws + 4096;             // 4096
    float* kq  = ws + 8192;             // 32768
    float* qkb = ws + 40960;            // 128
    float* g   = ws + 41088;            // 4096
    float* gz  = ws + 45184;            // 4096
    float* xa  = ws + 49280;            // 2 x 32768 = 65536
    float* e   = ws + 114816;           // 16*8*4096 = 524288 (2 MiB)
    float* ms  = ws + 639104;           // 16*8*16*2 = 4096

    float* out  = (float*)d_out;
    float* attn = out + (size_t)B_ * C_ * T_;    // output #1 region

    k_t1gate<<<16, 512, 0, stream>>>(F_text, F_unified, F_teacher,
                                     tp_w1, tp_b1, fa_w, fa_b, gp_w, gp_b,
                                     t1, g);
    gemm16<256, 0><<<16, 512, 0, stream>>>(t1, tp_w2, tp_b2, tv);
    k_qkq<<<NH_, 512, 0, stream>>>(tv, q_w, q_b, k_w, k_b, kq, qkb);

    k2_scores<<<dim3(16, B_), 256, 0, stream>>>(F_vis, kq, qkb, e, ms);
    k4_xa<<<dim3(16, B_, 2), 256, 0, stream>>>(F_vis, e, ms, attn, xa);
    k5_z<<<B_, 256, 0, stream>>>(xa, v_w, v_b, o_w, o_b, g, gz);
    k6_ln<<<dim3(128, B_), 256, 0, stream>>>(F_vis, gz, ln_g, ln_b, out);
}

// Round 8
// 105.448 us; speedup vs baseline: 1.1175x; 1.1175x over previous
//
#include <hip/hip_runtime.h>
#include <math.h>

#define B_  16
#define C_  256
#define T_  4096
#define DT_ 512
#define NH_ 8
#define HD_ 32

// ---------------------------------------------------------------------------
// k_t1gate (16 blocks x 512 thr): t1 = gelu(F_text@tp_w1+b1); gate g.
// ---------------------------------------------------------------------------
__global__ __launch_bounds__(512) void k_t1gate(
    const float* __restrict__ F_text, const float* __restrict__ U,
    const float* __restrict__ Tt,
    const float* __restrict__ tp_w1, const float* __restrict__ tp_b1,
    const float* __restrict__ fa_w,  const float* __restrict__ fa_b,
    const float* __restrict__ gp_w,  const float* __restrict__ gp_b,
    float* __restrict__ t1, float* __restrict__ gout)
{
    __shared__ float xs[8192];
    __shared__ float part[8192];
    __shared__ float pd[2][16][32];
    __shared__ float a0s[16], a1s[16];
    int tid = threadIdx.x;
    int c0  = blockIdx.x * 16;
    int cl  = tid & 15, ks = tid >> 4;
    int c   = c0 + cl;

    for (int idx = tid; idx < 8192; idx += 512) xs[idx] = F_text[idx];
    __syncthreads();
    {
        float acc[16];
        #pragma unroll
        for (int b = 0; b < 16; ++b) acc[b] = 0.f;
        const float* wp = tp_w1 + (size_t)(ks * 16) * 256 + c;
        #pragma unroll
        for (int i = 0; i < 16; ++i) {
            float w = wp[(size_t)i * 256];
            int xi = ks * 16 + i;
            #pragma unroll
            for (int b = 0; b < 16; ++b) acc[b] += xs[b * 512 + xi] * w;
        }
        #pragma unroll
        for (int b = 0; b < 16; ++b) part[ks * 256 + b * 16 + cl] = acc[b];
    }
    __syncthreads();
    if (tid < 256) {
        int b = tid >> 4, cc = tid & 15;
        float s = 0.f;
        #pragma unroll
        for (int k2 = 0; k2 < 32; ++k2) s += part[k2 * 256 + b * 16 + cc];
        s += tp_b1[c0 + cc];
        s = 0.5f * s * (1.0f + erff(s * 0.70710678118654752f));
        t1[b * 256 + c0 + cc] = s;
    }
    __syncthreads();

    {
        int b = tid >> 5, sl = tid & 31;
        const float* ub = U  + b * 512 + sl * 16;
        const float* tb = Tt + b * 512 + sl * 16;
        const float* fw = fa_w + sl * 16;
        float su = 0.f, st = 0.f;
        #pragma unroll
        for (int j = 0; j < 16; ++j) { su += ub[j] * fw[j]; st += tb[j] * fw[j]; }
        pd[0][b][sl] = su; pd[1][b][sl] = st;
    }
    __syncthreads();
    if (tid < 16) {
        float s0 = fa_b[0], s1 = fa_b[0];
        #pragma unroll
        for (int sl = 0; sl < 32; ++sl) { s0 += pd[0][tid][sl]; s1 += pd[1][tid][sl]; }
        float mm = fmaxf(s0, s1);
        float e0 = expf(s0 - mm), e1 = expf(s1 - mm);
        float inv = 1.0f / (e0 + e1);
        a0s[tid] = e0 * inv; a1s[tid] = e1 * inv;
    }
    __syncthreads();
    for (int idx = tid; idx < 8192; idx += 512) {
        int b = idx >> 9;
        xs[idx] = a0s[b] * U[idx] + a1s[b] * Tt[idx];
    }
    __syncthreads();
    {
        float acc[16];
        #pragma unroll
        for (int b = 0; b < 16; ++b) acc[b] = 0.f;
        const float* wp = gp_w + (size_t)(ks * 16) * 256 + c;
        #pragma unroll
        for (int i = 0; i < 16; ++i) {
            float w = wp[(size_t)i * 256];
            int xi = ks * 16 + i;
            #pragma unroll
            for (int b = 0; b < 16; ++b) acc[b] += xs[b * 512 + xi] * w;
        }
        #pragma unroll
        for (int b = 0; b < 16; ++b) part[ks * 256 + b * 16 + cl] = acc[b];
    }
    __syncthreads();
    if (tid < 256) {
        int b = tid >> 4, cc = tid & 15;
        float s = 0.f;
        #pragma unroll
        for (int k2 = 0; k2 < 32; ++k2) s += part[k2 * 256 + b * 16 + cc];
        s += gp_b[c0 + cc];
        gout[b * 256 + c0 + cc] = 1.0f / (1.0f + expf(-s));
    }
}

// ---------------------------------------------------------------------------
// gemm16<K,ACT>: out[16][256] = act(x[16][K] @ W[K][256] + bias)  (tv step)
// ---------------------------------------------------------------------------
template<int K, int ACT>
__global__ __launch_bounds__(512) void gemm16(const float* __restrict__ x,
                                              const float* __restrict__ W,
                                              const float* __restrict__ bias,
                                              float* __restrict__ out)
{
    __shared__ float xs[16 * K];
    __shared__ float part[32 * 256];
    int tid = threadIdx.x;
    int c0  = blockIdx.x * 16;

    for (int idx = tid; idx < 16 * K; idx += 512) xs[idx] = x[idx];
    __syncthreads();

    int cl = tid & 15, ks = tid >> 4;
    const int Kc = K / 32;
    int c = c0 + cl;

    float acc[16];
    #pragma unroll
    for (int b = 0; b < 16; ++b) acc[b] = 0.f;

    const float* wp = W + (size_t)(ks * Kc) * 256 + c;
    #pragma unroll
    for (int i = 0; i < Kc; ++i) {
        float w  = wp[(size_t)i * 256];
        int   xi = ks * Kc + i;
        #pragma unroll
        for (int b = 0; b < 16; ++b) acc[b] += xs[b * K + xi] * w;
    }
    #pragma unroll
    for (int b = 0; b < 16; ++b) part[ks * 256 + b * 16 + cl] = acc[b];
    __syncthreads();

    if (tid < 256) {
        int b = tid >> 4, cc = tid & 15;
        float s = 0.f;
        #pragma unroll
        for (int k2 = 0; k2 < 32; ++k2) s += part[k2 * 256 + b * 16 + cc];
        s += bias[c0 + cc];
        if (ACT == 1) s = 0.5f * s * (1.0f + erff(s * 0.70710678118654752f));
        out[b * 256 + c0 + cc] = s;
    }
}

// ---------------------------------------------------------------------------
// k_qkq (8 blocks = 1 head each, 512 thr): q-slice + kq + qkb fused.
// ---------------------------------------------------------------------------
__global__ __launch_bounds__(512) void k_qkq(const float* __restrict__ tv,
                                             const float* __restrict__ q_w,
                                             const float* __restrict__ q_b,
                                             const float* __restrict__ k_w,
                                             const float* __restrict__ k_b,
                                             float* __restrict__ kq,
                                             float* __restrict__ qkb)
{
    __shared__ float xs[4096];
    __shared__ float part[8192];
    __shared__ float qs[512];
    int tid = threadIdx.x;
    int h   = blockIdx.x;

    for (int idx = tid; idx < 4096; idx += 512) xs[idx] = tv[idx];
    __syncthreads();

    {
        int cl = tid & 31, ks = tid >> 5;
        float acc[16];
        #pragma unroll
        for (int b = 0; b < 16; ++b) acc[b] = 0.f;
        const float* wp = q_w + (size_t)(ks * 16) * 256 + h * HD_ + cl;
        #pragma unroll
        for (int i = 0; i < 16; ++i) {
            float w = wp[(size_t)i * 256];
            int xi = ks * 16 + i;
            #pragma unroll
            for (int b = 0; b < 16; ++b) acc[b] += xs[b * 256 + xi] * w;
        }
        #pragma unroll
        for (int b = 0; b < 16; ++b) part[(ks * 16 + b) * 32 + cl] = acc[b];
    }
    __syncthreads();
    {
        int b = tid >> 5, cl = tid & 31;
        float s = 0.f;
        #pragma unroll
        for (int k2 = 0; k2 < 16; ++k2) s += part[(k2 * 16 + b) * 32 + cl];
        qs[b * 32 + cl] = s + q_b[h * HD_ + cl];
    }
    __syncthreads();
    if (tid < 16) {
        float s = 0.f;
        #pragma unroll
        for (int d = 0; d < 32; ++d) s += qs[tid * 32 + d] * k_b[h * HD_ + d];
        qkb[tid * NH_ + h] = s;
    }

    {
        int c = tid >> 1, bh = tid & 1;
        const float4* kwp = reinterpret_cast<const float4*>(k_w + (size_t)c * 256 + h * HD_);
        float4 kw[8];
        #pragma unroll
        for (int j = 0; j < 8; ++j) kw[j] = kwp[j];
        float acc[8] = {0,0,0,0,0,0,0,0};
        #pragma unroll
        for (int j = 0; j < 8; ++j) {
            float w0 = kw[j].x, w1 = kw[j].y, w2 = kw[j].z, w3 = kw[j].w;
            #pragma unroll
            for (int bi = 0; bi < 8; ++bi) {
                const float* qp = &qs[(bh * 8 + bi) * 32 + j * 4];
                acc[bi] += qp[0] * w0 + qp[1] * w1 + qp[2] * w2 + qp[3] * w3;
            }
        }
        #pragma unroll
        for (int bi = 0; bi < 8; ++bi)
            kq[((size_t)((bh * 8 + bi) * NH_ + h)) * C_ + c] = acc[bi];
    }
}

// ---------------------------------------------------------------------------
// K2s: per 256-t chunk: scores (8-wave split-K) -> chunk softmax ->
//   e to ws, (m,sum) to ms, AND chunk-partial xa:
//   xac[ck][b][h][c] = sum_{t in ck} e_local[h][t] * F_vis[b,c,t]
// grid (16 tc, 16 b), 512 thr.
// ---------------------------------------------------------------------------
__global__ __launch_bounds__(512) void k2_scores(const float* __restrict__ F_vis,
                                                 const float* __restrict__ kq,
                                                 const float* __restrict__ qkb,
                                                 float* __restrict__ e,
                                                 float* __restrict__ ms,
                                                 float* __restrict__ xac)
{
    int tc = blockIdx.x;
    int b  = blockIdx.y;
    int tid = threadIdx.x;
    int t0 = tc * 256;
    const float scale = 0.176776695296636893f;   // 32^-0.5

    __shared__ float kqs[256][9];
    __shared__ __align__(16) float4 part4[8 * 8 * 64];   // [cs][h][t4]  64KB
    __shared__ __align__(16) float esf[8 * 256];         // e_local [h][t] 8KB
    __shared__ float qkbs[8];
    __shared__ float redm[8][4], reds[8][4];

    for (int idx = tid; idx < 2048; idx += 512) {
        int c = idx & 255, h = idx >> 8;
        kqs[c][h] = kq[((size_t)(b * NH_ + h)) * C_ + c];
    }
    if (tid < 8) qkbs[tid] = qkb[b * NH_ + tid];
    __syncthreads();

    // ---- phase 1: score partials (cs = c-slice, t4 = t-quad)
    {
        int cs = tid >> 6, t4 = tid & 63;
        const float* fv = F_vis + ((size_t)b * C_) * T_ + t0 + t4 * 4;
        float4 acc[8];
        #pragma unroll
        for (int h = 0; h < 8; ++h) acc[h] = make_float4(0.f, 0.f, 0.f, 0.f);
        #pragma unroll 8
        for (int i = 0; i < 32; ++i) {
            int c = i * 8 + cs;
            float4 v = *reinterpret_cast<const float4*>(&fv[(size_t)c * T_]);
            #pragma unroll
            for (int h = 0; h < 8; ++h) {
                float w = kqs[c][h];
                acc[h].x += v.x * w; acc[h].y += v.y * w;
                acc[h].z += v.z * w; acc[h].w += v.w * w;
            }
        }
        #pragma unroll
        for (int h = 0; h < 8; ++h) part4[(cs * 8 + h) * 64 + t4] = acc[h];
    }
    __syncthreads();

    // ---- phase 2: chunk softmax (tl = t, hg picks 4 heads)
    {
        int tl = tid & 255, hg = tid >> 8;
        int lane = tid & 63, wid = tid >> 6;
        const float* pf = reinterpret_cast<const float*>(part4);
        float sv[4], mh[4];
        #pragma unroll
        for (int hh = 0; hh < 4; ++hh) {
            int h = hg * 4 + hh;
            float s = 0.f;
            #pragma unroll
            for (int cs = 0; cs < 8; ++cs) s += pf[(cs * 8 + h) * 256 + tl];
            sv[hh] = (s + qkbs[h]) * scale;
            float m = sv[hh];
            #pragma unroll
            for (int o = 32; o; o >>= 1) m = fmaxf(m, __shfl_xor(m, o));
            mh[hh] = m;
        }
        if (lane == 0) {
            #pragma unroll
            for (int hh = 0; hh < 4; ++hh) redm[hg * 4 + hh][wid & 3] = mh[hh];
        }
        __syncthreads();
        float ev[4];
        #pragma unroll
        for (int hh = 0; hh < 4; ++hh) {
            int h = hg * 4 + hh;
            float m = fmaxf(fmaxf(redm[h][0], redm[h][1]), fmaxf(redm[h][2], redm[h][3]));
            ev[hh] = expf(sv[hh] - m);
            e[((size_t)(b * NH_ + h)) * T_ + t0 + tl] = ev[hh];
            esf[h * 256 + tl] = ev[hh];
            float sm = ev[hh];
            #pragma unroll
            for (int o = 32; o; o >>= 1) sm += __shfl_xor(sm, o);
            if (lane == 0) reds[h][wid & 3] = sm;
        }
        __syncthreads();
        if (tid < 8) {
            float m = fmaxf(fmaxf(redm[tid][0], redm[tid][1]),
                            fmaxf(redm[tid][2], redm[tid][3]));
            float sum = reds[tid][0] + reds[tid][1] + reds[tid][2] + reds[tid][3];
            size_t base = (((size_t)(b * NH_ + tid)) * 16 + tc) * 2;
            ms[base]     = m;
            ms[base + 1] = sum;
        }
    }

    // ---- phase 3: chunk xa partial.  wave = 16 c x 4 t-quarters.
    {
        int lane = tid & 63, wid = tid >> 6;
        int cl = lane & 15, tq = lane >> 4;
        const float4* es4 = reinterpret_cast<const float4*>(esf);   // [h][64]
        #pragma unroll
        for (int pass = 0; pass < 2; ++pass) {
            int c = pass * 128 + wid * 16 + cl;
            const float* fvc = F_vis + ((size_t)b * C_ + c) * T_ + t0;
            float p[8] = {0, 0, 0, 0, 0, 0, 0, 0};
            #pragma unroll 4
            for (int i = 0; i < 16; ++i) {
                int Q = tq * 16 + i;
                float4 v = *reinterpret_cast<const float4*>(&fvc[Q * 4]);
                #pragma unroll
                for (int h = 0; h < 8; ++h) {
                    float4 E = es4[h * 64 + Q];
                    p[h] += v.x * E.x + v.y * E.y + v.z * E.z + v.w * E.w;
                }
            }
            #pragma unroll
            for (int h = 0; h < 8; ++h) {
                p[h] += __shfl_xor(p[h], 16);
                p[h] += __shfl_xor(p[h], 32);
            }
            if (tq == 0) {
                #pragma unroll
                for (int h = 0; h < 8; ++h)
                    xac[(((size_t)tc * B_ + b) * NH_ + h) * C_ + c] = p[h];
            }
        }
    }
}

// ---------------------------------------------------------------------------
// K5m: merge chunk stats -> fact; attn = e*fact; xa = sum_ck xac*fact;
//      z = (xa@v_w+v_b)@o_w+o_b; gz = g*z.   grid B_, 256 thr.
// ---------------------------------------------------------------------------
__global__ __launch_bounds__(256) void k5_merge(const float* __restrict__ e,
                                               const float* __restrict__ ms,
                                               const float* __restrict__ xac,
                                               const float* __restrict__ v_w,
                                               const float* __restrict__ v_b,
                                               const float* __restrict__ o_w,
                                               const float* __restrict__ o_b,
                                               const float* __restrict__ g,
                                               float* __restrict__ attn,
                                               float* __restrict__ gz)
{
    int b = blockIdx.x, tid = threadIdx.x;
    __shared__ float fact[8][16];
    __shared__ float xaL[8][256];
    __shared__ float zp[256];
    __shared__ float Ms[8], iZs[8];

    if (tid < 8) {
        const float* mp = ms + ((size_t)(b * NH_ + tid)) * 32;
        float M = -1e30f;
        #pragma unroll
        for (int ck = 0; ck < 16; ++ck) M = fmaxf(M, mp[ck * 2]);
        float Z = 0.f;
        #pragma unroll
        for (int ck = 0; ck < 16; ++ck) Z += mp[ck * 2 + 1] * expf(mp[ck * 2] - M);
        Ms[tid] = M; iZs[tid] = 1.0f / Z;
    }
    __syncthreads();
    if (tid < 128) {
        int h = tid >> 4, ck = tid & 15;
        fact[h][ck] = expf(ms[((size_t)(b * NH_ + h)) * 32 + ck * 2] - Ms[h]) * iZs[h];
    }
    __syncthreads();

    // attn = e * fact
    const float4* eb = reinterpret_cast<const float4*>(e + (size_t)b * NH_ * T_);
    float4* ab = reinterpret_cast<float4*>(attn + (size_t)b * NH_ * T_);
    for (int idx = tid; idx < NH_ * T_ / 4; idx += 256) {
        int h  = idx >> 10;
        int tq = idx & 1023;
        float f = fact[h][tq >> 6];
        float4 a = eb[idx];
        a.x *= f; a.y *= f; a.z *= f; a.w *= f;
        ab[idx] = a;
    }

    // xa merge
    for (int idx = tid; idx < 2048; idx += 256) {
        int h = idx >> 8, c = idx & 255;
        float s = 0.f;
        #pragma unroll
        for (int ck = 0; ck < 16; ++ck)
            s += xac[(((size_t)ck * B_ + b) * NH_ + h) * C_ + c] * fact[h][ck];
        xaL[h][c] = s;
    }
    __syncthreads();

    // v GEMM then o GEMM
    {
        int h = tid >> 5;
        float s = v_b[tid];
        #pragma unroll 8
        for (int c = 0; c < 256; ++c) s += xaL[h][c] * v_w[c * 256 + tid];
        zp[tid] = s;
    }
    __syncthreads();
    {
        float z = o_b[tid];
        #pragma unroll 8
        for (int i = 0; i < 256; ++i) z += zp[i] * o_w[i * 256 + tid];
        gz[b * 256 + tid] = g[b * 256 + tid] * z;
    }
}

// ---------------------------------------------------------------------------
// K6: fused residual+gate+LayerNorm, register-resident, shfl-reduce.
// ---------------------------------------------------------------------------
__global__ __launch_bounds__(256) void k6_ln(const float* __restrict__ F_vis,
                                             const float* __restrict__ gz,
                                             const float* __restrict__ ln_g,
                                             const float* __restrict__ ln_b,
                                             float* __restrict__ out)
{
    int b  = blockIdx.y;
    int t0 = blockIdx.x * 32;
    int tid = threadIdx.x;
    int t4 = tid & 7;
    int cb = tid >> 3;

    __shared__ float gzs[256], lgs[256], lbs[256];
    __shared__ float4 redS[4][8], redQ[4][8];
    __shared__ float4 mu4s[8], rs4s[8];

    gzs[tid] = gz[b * C_ + tid];
    lgs[tid] = ln_g[tid];
    lbs[tid] = ln_b[tid];
    __syncthreads();

    const float* fvb = F_vis + (size_t)b * C_ * T_ + t0 + t4 * 4;
    float4 v[8];
    float4 s = make_float4(0.f, 0.f, 0.f, 0.f);
    float4 q = make_float4(0.f, 0.f, 0.f, 0.f);
    #pragma unroll
    for (int k = 0; k < 8; ++k) {
        int c = cb + k * 32;
        float4 x = *reinterpret_cast<const float4*>(&fvb[(size_t)c * T_]);
        float gc = gzs[c];
        x.x += gc; x.y += gc; x.z += gc; x.w += gc;
        v[k] = x;
        s.x += x.x; s.y += x.y; s.z += x.z; s.w += x.w;
        q.x += x.x * x.x; q.y += x.y * x.y; q.z += x.z * x.z; q.w += x.w * x.w;
    }
    #pragma unroll
    for (int o = 8; o <= 32; o <<= 1) {
        s.x += __shfl_xor(s.x, o); s.y += __shfl_xor(s.y, o);
        s.z += __shfl_xor(s.z, o); s.w += __shfl_xor(s.w, o);
        q.x += __shfl_xor(q.x, o); q.y += __shfl_xor(q.y, o);
        q.z += __shfl_xor(q.z, o); q.w += __shfl_xor(q.w, o);
    }
    int wid = tid >> 6;
    if ((tid & 63) < 8) { redS[wid][t4] = s; redQ[wid][t4] = q; }
    __syncthreads();
    if (tid < 8) {
        float4 S = redS[0][tid], Q = redQ[0][tid];
        #pragma unroll
        for (int w = 1; w < 4; ++w) {
            float4 a = redS[w][tid], c2 = redQ[w][tid];
            S.x += a.x; S.y += a.y; S.z += a.z; S.w += a.w;
            Q.x += c2.x; Q.y += c2.y; Q.z += c2.z; Q.w += c2.w;
        }
        float4 mu, rs;
        mu.x = S.x * (1.0f / C_); mu.y = S.y * (1.0f / C_);
        mu.z = S.z * (1.0f / C_); mu.w = S.w * (1.0f / C_);
        rs.x = rsqrtf(fmaxf(Q.x * (1.0f / C_) - mu.x * mu.x, 0.f) + 1e-5f);
        rs.y = rsqrtf(fmaxf(Q.y * (1.0f / C_) - mu.y * mu.y, 0.f) + 1e-5f);
        rs.z = rsqrtf(fmaxf(Q.z * (1.0f / C_) - mu.z * mu.z, 0.f) + 1e-5f);
        rs.w = rsqrtf(fmaxf(Q.w * (1.0f / C_) - mu.w * mu.w, 0.f) + 1e-5f);
        mu4s[tid] = mu; rs4s[tid] = rs;
    }
    __syncthreads();
    float4 mu = mu4s[t4], rs = rs4s[t4];
    float* ob = out + (size_t)b * C_ * T_ + t0 + t4 * 4;
    #pragma unroll
    for (int k = 0; k < 8; ++k) {
        int c = cb + k * 32;
        float lg = lgs[c], lb = lbs[c];
        float4 o;
        o.x = (v[k].x - mu.x) * rs.x * lg + lb;
        o.y = (v[k].y - mu.y) * rs.y * lg + lb;
        o.z = (v[k].z - mu.z) * rs.z * lg + lb;
        o.w = (v[k].w - mu.w) * rs.w * lg + lb;
        *reinterpret_cast<float4*>(&ob[(size_t)c * T_]) = o;
    }
}

// ---------------------------------------------------------------------------
extern "C" void kernel_launch(void* const* d_in, const int* in_sizes, int n_in,
                              void* d_out, int out_size, void* d_ws, size_t ws_size,
                              hipStream_t stream)
{
    const float* F_vis     = (const float*)d_in[0];
    const float* F_text    = (const float*)d_in[1];
    const float* F_unified = (const float*)d_in[2];
    const float* F_teacher = (const float*)d_in[3];
    const float* tp_w1 = (const float*)d_in[4];
    const float* tp_b1 = (const float*)d_in[5];
    const float* tp_w2 = (const float*)d_in[6];
    const float* tp_b2 = (const float*)d_in[7];
    const float* q_w   = (const float*)d_in[8];
    const float* q_b   = (const float*)d_in[9];
    const float* k_w   = (const float*)d_in[10];
    const float* k_b   = (const float*)d_in[11];
    const float* v_w   = (const float*)d_in[12];
    const float* v_b   = (const float*)d_in[13];
    const float* o_w   = (const float*)d_in[14];
    const float* o_b   = (const float*)d_in[15];
    const float* fa_w  = (const float*)d_in[16];
    const float* fa_b  = (const float*)d_in[17];
    const float* gp_w  = (const float*)d_in[18];
    const float* gp_b  = (const float*)d_in[19];
    const float* ln_g  = (const float*)d_in[20];
    const float* ln_b  = (const float*)d_in[21];

    float* ws  = (float*)d_ws;
    float* t1  = ws;                    // 4096
    float* tv  = ws + 4096;             // 4096
    float* kq  = ws + 8192;             // 32768
    float* qkb = ws + 40960;            // 128
    float* g   = ws + 41088;            // 4096
    float* gz  = ws + 45184;            // 4096
    float* e   = ws + 49280;            // 524288 (2 MiB)
    float* ms  = ws + 573568;           // 4096
    float* xac = ws + 577664;           // 524288 (2 MiB)

    float* out  = (float*)d_out;
    float* attn = out + (size_t)B_ * C_ * T_;    // output #1 region

    k_t1gate<<<16, 512, 0, stream>>>(F_text, F_unified, F_teacher,
                                     tp_w1, tp_b1, fa_w, fa_b, gp_w, gp_b,
                                     t1, g);
    gemm16<256, 0><<<16, 512, 0, stream>>>(t1, tp_w2, tp_b2, tv);
    k_qkq<<<NH_, 512, 0, stream>>>(tv, q_w, q_b, k_w, k_b, kq, qkb);

    k2_scores<<<dim3(16, B_), 512, 0, stream>>>(F_vis, kq, qkb, e, ms, xac);
    k5_merge<<<B_, 256, 0, stream>>>(e, ms, xac, v_w, v_b, o_w, o_b, g, attn, gz);
    k6_ln<<<dim3(128, B_), 256, 0, stream>>>(F_vis, gz, ln_g, ln_b, out);
}

// Round 9
// 88.679 us; speedup vs baseline: 1.3288x; 1.1891x over previous
//
#include <hip/hip_runtime.h>
#include <math.h>

#define B_  16
#define C_  256
#define T_  4096
#define DT_ 512
#define NH_ 8
#define HD_ 32

// ---------------------------------------------------------------------------
// k_t1gate (16 blocks x 512 thr): t1 = gelu(F_text@tp_w1+b1); gate g.
// ---------------------------------------------------------------------------
__global__ __launch_bounds__(512) void k_t1gate(
    const float* __restrict__ F_text, const float* __restrict__ U,
    const float* __restrict__ Tt,
    const float* __restrict__ tp_w1, const float* __restrict__ tp_b1,
    const float* __restrict__ fa_w,  const float* __restrict__ fa_b,
    const float* __restrict__ gp_w,  const float* __restrict__ gp_b,
    float* __restrict__ t1, float* __restrict__ gout)
{
    __shared__ float xs[8192];
    __shared__ float part[8192];
    __shared__ float pd[2][16][32];
    __shared__ float a0s[16], a1s[16];
    int tid = threadIdx.x;
    int c0  = blockIdx.x * 16;
    int cl  = tid & 15, ks = tid >> 4;
    int c   = c0 + cl;

    for (int idx = tid; idx < 8192; idx += 512) xs[idx] = F_text[idx];
    __syncthreads();
    {
        float acc[16];
        #pragma unroll
        for (int b = 0; b < 16; ++b) acc[b] = 0.f;
        const float* wp = tp_w1 + (size_t)(ks * 16) * 256 + c;
        #pragma unroll
        for (int i = 0; i < 16; ++i) {
            float w = wp[(size_t)i * 256];
            int xi = ks * 16 + i;
            #pragma unroll
            for (int b = 0; b < 16; ++b) acc[b] += xs[b * 512 + xi] * w;
        }
        #pragma unroll
        for (int b = 0; b < 16; ++b) part[ks * 256 + b * 16 + cl] = acc[b];
    }
    __syncthreads();
    if (tid < 256) {
        int b = tid >> 4, cc = tid & 15;
        float s = 0.f;
        #pragma unroll
        for (int k2 = 0; k2 < 32; ++k2) s += part[k2 * 256 + b * 16 + cc];
        s += tp_b1[c0 + cc];
        s = 0.5f * s * (1.0f + erff(s * 0.70710678118654752f));
        t1[b * 256 + c0 + cc] = s;
    }
    __syncthreads();

    {
        int b = tid >> 5, sl = tid & 31;
        const float* ub = U  + b * 512 + sl * 16;
        const float* tb = Tt + b * 512 + sl * 16;
        const float* fw = fa_w + sl * 16;
        float su = 0.f, st = 0.f;
        #pragma unroll
        for (int j = 0; j < 16; ++j) { su += ub[j] * fw[j]; st += tb[j] * fw[j]; }
        pd[0][b][sl] = su; pd[1][b][sl] = st;
    }
    __syncthreads();
    if (tid < 16) {
        float s0 = fa_b[0], s1 = fa_b[0];
        #pragma unroll
        for (int sl = 0; sl < 32; ++sl) { s0 += pd[0][tid][sl]; s1 += pd[1][tid][sl]; }
        float mm = fmaxf(s0, s1);
        float e0 = expf(s0 - mm), e1 = expf(s1 - mm);
        float inv = 1.0f / (e0 + e1);
        a0s[tid] = e0 * inv; a1s[tid] = e1 * inv;
    }
    __syncthreads();
    for (int idx = tid; idx < 8192; idx += 512) {
        int b = idx >> 9;
        xs[idx] = a0s[b] * U[idx] + a1s[b] * Tt[idx];
    }
    __syncthreads();
    {
        float acc[16];
        #pragma unroll
        for (int b = 0; b < 16; ++b) acc[b] = 0.f;
        const float* wp = gp_w + (size_t)(ks * 16) * 256 + c;
        #pragma unroll
        for (int i = 0; i < 16; ++i) {
            float w = wp[(size_t)i * 256];
            int xi = ks * 16 + i;
            #pragma unroll
            for (int b = 0; b < 16; ++b) acc[b] += xs[b * 512 + xi] * w;
        }
        #pragma unroll
        for (int b = 0; b < 16; ++b) part[ks * 256 + b * 16 + cl] = acc[b];
    }
    __syncthreads();
    if (tid < 256) {
        int b = tid >> 4, cc = tid & 15;
        float s = 0.f;
        #pragma unroll
        for (int k2 = 0; k2 < 32; ++k2) s += part[k2 * 256 + b * 16 + cc];
        s += gp_b[c0 + cc];
        gout[b * 256 + c0 + cc] = 1.0f / (1.0f + expf(-s));
    }
}

// ---------------------------------------------------------------------------
// gemm16<K,ACT>: out[16][256] = act(x[16][K] @ W[K][256] + bias)  (tv step)
// ---------------------------------------------------------------------------
template<int K, int ACT>
__global__ __launch_bounds__(512) void gemm16(const float* __restrict__ x,
                                              const float* __restrict__ W,
                                              const float* __restrict__ bias,
                                              float* __restrict__ out)
{
    __shared__ float xs[16 * K];
    __shared__ float part[32 * 256];
    int tid = threadIdx.x;
    int c0  = blockIdx.x * 16;

    for (int idx = tid; idx < 16 * K; idx += 512) xs[idx] = x[idx];
    __syncthreads();

    int cl = tid & 15, ks = tid >> 4;
    const int Kc = K / 32;
    int c = c0 + cl;

    float acc[16];
    #pragma unroll
    for (int b = 0; b < 16; ++b) acc[b] = 0.f;

    const float* wp = W + (size_t)(ks * Kc) * 256 + c;
    #pragma unroll
    for (int i = 0; i < Kc; ++i) {
        float w  = wp[(size_t)i * 256];
        int   xi = ks * Kc + i;
        #pragma unroll
        for (int b = 0; b < 16; ++b) acc[b] += xs[b * K + xi] * w;
    }
    #pragma unroll
    for (int b = 0; b < 16; ++b) part[ks * 256 + b * 16 + cl] = acc[b];
    __syncthreads();

    if (tid < 256) {
        int b = tid >> 4, cc = tid & 15;
        float s = 0.f;
        #pragma unroll
        for (int k2 = 0; k2 < 32; ++k2) s += part[k2 * 256 + b * 16 + cc];
        s += bias[c0 + cc];
        if (ACT == 1) s = 0.5f * s * (1.0f + erff(s * 0.70710678118654752f));
        out[b * 256 + c0 + cc] = s;
    }
}

// ---------------------------------------------------------------------------
// k_qkq (8 blocks = 1 head each, 512 thr): q-slice + kq + qkb fused.
// ---------------------------------------------------------------------------
__global__ __launch_bounds__(512) void k_qkq(const float* __restrict__ tv,
                                             const float* __restrict__ q_w,
                                             const float* __restrict__ q_b,
                                             const float* __restrict__ k_w,
                                             const float* __restrict__ k_b,
                                             float* __restrict__ kq,
                                             float* __restrict__ qkb)
{
    __shared__ float xs[4096];
    __shared__ float part[8192];
    __shared__ float qs[512];
    int tid = threadIdx.x;
    int h   = blockIdx.x;

    for (int idx = tid; idx < 4096; idx += 512) xs[idx] = tv[idx];
    __syncthreads();

    {
        int cl = tid & 31, ks = tid >> 5;
        float acc[16];
        #pragma unroll
        for (int b = 0; b < 16; ++b) acc[b] = 0.f;
        const float* wp = q_w + (size_t)(ks * 16) * 256 + h * HD_ + cl;
        #pragma unroll
        for (int i = 0; i < 16; ++i) {
            float w = wp[(size_t)i * 256];
            int xi = ks * 16 + i;
            #pragma unroll
            for (int b = 0; b < 16; ++b) acc[b] += xs[b * 256 + xi] * w;
        }
        #pragma unroll
        for (int b = 0; b < 16; ++b) part[(ks * 16 + b) * 32 + cl] = acc[b];
    }
    __syncthreads();
    {
        int b = tid >> 5, cl = tid & 31;
        float s = 0.f;
        #pragma unroll
        for (int k2 = 0; k2 < 16; ++k2) s += part[(k2 * 16 + b) * 32 + cl];
        qs[b * 32 + cl] = s + q_b[h * HD_ + cl];
    }
    __syncthreads();
    if (tid < 16) {
        float s = 0.f;
        #pragma unroll
        for (int d = 0; d < 32; ++d) s += qs[tid * 32 + d] * k_b[h * HD_ + d];
        qkb[tid * NH_ + h] = s;
    }

    {
        int c = tid >> 1, bh = tid & 1;
        const float4* kwp = reinterpret_cast<const float4*>(k_w + (size_t)c * 256 + h * HD_);
        float4 kw[8];
        #pragma unroll
        for (int j = 0; j < 8; ++j) kw[j] = kwp[j];
        float acc[8] = {0,0,0,0,0,0,0,0};
        #pragma unroll
        for (int j = 0; j < 8; ++j) {
            float w0 = kw[j].x, w1 = kw[j].y, w2 = kw[j].z, w3 = kw[j].w;
            #pragma unroll
            for (int bi = 0; bi < 8; ++bi) {
                const float* qp = &qs[(bh * 8 + bi) * 32 + j * 4];
                acc[bi] += qp[0] * w0 + qp[1] * w1 + qp[2] * w2 + qp[3] * w3;
            }
        }
        #pragma unroll
        for (int bi = 0; bi < 8; ++bi)
            kq[((size_t)((bh * 8 + bi) * NH_ + h)) * C_ + c] = acc[bi];
    }
}

// ---------------------------------------------------------------------------
// K2s: per 256-t chunk: scores (8-wave split-K) -> chunk softmax ->
//   e to ws, (m,sum) to ms, AND chunk-partial xa.
// ---------------------------------------------------------------------------
__global__ __launch_bounds__(512) void k2_scores(const float* __restrict__ F_vis,
                                                 const float* __restrict__ kq,
                                                 const float* __restrict__ qkb,
                                                 float* __restrict__ e,
                                                 float* __restrict__ ms,
                                                 float* __restrict__ xac)
{
    int tc = blockIdx.x;
    int b  = blockIdx.y;
    int tid = threadIdx.x;
    int t0 = tc * 256;
    const float scale = 0.176776695296636893f;   // 32^-0.5

    __shared__ float kqs[256][9];
    __shared__ __align__(16) float4 part4[8 * 8 * 64];   // [cs][h][t4]  64KB
    __shared__ __align__(16) float esf[8 * 256];         // e_local [h][t] 8KB
    __shared__ float qkbs[8];
    __shared__ float redm[8][4], reds[8][4];

    for (int idx = tid; idx < 2048; idx += 512) {
        int c = idx & 255, h = idx >> 8;
        kqs[c][h] = kq[((size_t)(b * NH_ + h)) * C_ + c];
    }
    if (tid < 8) qkbs[tid] = qkb[b * NH_ + tid];
    __syncthreads();

    // ---- phase 1: score partials (cs = c-slice, t4 = t-quad)
    {
        int cs = tid >> 6, t4 = tid & 63;
        const float* fv = F_vis + ((size_t)b * C_) * T_ + t0 + t4 * 4;
        float4 acc[8];
        #pragma unroll
        for (int h = 0; h < 8; ++h) acc[h] = make_float4(0.f, 0.f, 0.f, 0.f);
        #pragma unroll 8
        for (int i = 0; i < 32; ++i) {
            int c = i * 8 + cs;
            float4 v = *reinterpret_cast<const float4*>(&fv[(size_t)c * T_]);
            #pragma unroll
            for (int h = 0; h < 8; ++h) {
                float w = kqs[c][h];
                acc[h].x += v.x * w; acc[h].y += v.y * w;
                acc[h].z += v.z * w; acc[h].w += v.w * w;
            }
        }
        #pragma unroll
        for (int h = 0; h < 8; ++h) part4[(cs * 8 + h) * 64 + t4] = acc[h];
    }
    __syncthreads();

    // ---- phase 2: chunk softmax
    {
        int tl = tid & 255, hg = tid >> 8;
        int lane = tid & 63, wid = tid >> 6;
        const float* pf = reinterpret_cast<const float*>(part4);
        float sv[4], mh[4];
        #pragma unroll
        for (int hh = 0; hh < 4; ++hh) {
            int h = hg * 4 + hh;
            float s = 0.f;
            #pragma unroll
            for (int cs = 0; cs < 8; ++cs) s += pf[(cs * 8 + h) * 256 + tl];
            sv[hh] = (s + qkbs[h]) * scale;
            float m = sv[hh];
            #pragma unroll
            for (int o = 32; o; o >>= 1) m = fmaxf(m, __shfl_xor(m, o));
            mh[hh] = m;
        }
        if (lane == 0) {
            #pragma unroll
            for (int hh = 0; hh < 4; ++hh) redm[hg * 4 + hh][wid & 3] = mh[hh];
        }
        __syncthreads();
        float ev[4];
        #pragma unroll
        for (int hh = 0; hh < 4; ++hh) {
            int h = hg * 4 + hh;
            float m = fmaxf(fmaxf(redm[h][0], redm[h][1]), fmaxf(redm[h][2], redm[h][3]));
            ev[hh] = expf(sv[hh] - m);
            e[((size_t)(b * NH_ + h)) * T_ + t0 + tl] = ev[hh];
            esf[h * 256 + tl] = ev[hh];
            float sm = ev[hh];
            #pragma unroll
            for (int o = 32; o; o >>= 1) sm += __shfl_xor(sm, o);
            if (lane == 0) reds[h][wid & 3] = sm;
        }
        __syncthreads();
        if (tid < 8) {
            float m = fmaxf(fmaxf(redm[tid][0], redm[tid][1]),
                            fmaxf(redm[tid][2], redm[tid][3]));
            float sum = reds[tid][0] + reds[tid][1] + reds[tid][2] + reds[tid][3];
            size_t base = (((size_t)(b * NH_ + tid)) * 16 + tc) * 2;
            ms[base]     = m;
            ms[base + 1] = sum;
        }
    }

    // ---- phase 3: chunk xa partial.  wave = 16 c x 4 t-quarters.
    {
        int lane = tid & 63, wid = tid >> 6;
        int cl = lane & 15, tq = lane >> 4;
        const float4* es4 = reinterpret_cast<const float4*>(esf);   // [h][64]
        #pragma unroll
        for (int pass = 0; pass < 2; ++pass) {
            int c = pass * 128 + wid * 16 + cl;
            const float* fvc = F_vis + ((size_t)b * C_ + c) * T_ + t0;
            float p[8] = {0, 0, 0, 0, 0, 0, 0, 0};
            #pragma unroll 4
            for (int i = 0; i < 16; ++i) {
                int Q = tq * 16 + i;
                float4 v = *reinterpret_cast<const float4*>(&fvc[Q * 4]);
                #pragma unroll
                for (int h = 0; h < 8; ++h) {
                    float4 E = es4[h * 64 + Q];
                    p[h] += v.x * E.x + v.y * E.y + v.z * E.z + v.w * E.w;
                }
            }
            #pragma unroll
            for (int h = 0; h < 8; ++h) {
                p[h] += __shfl_xor(p[h], 16);
                p[h] += __shfl_xor(p[h], 32);
            }
            if (tq == 0) {
                #pragma unroll
                for (int h = 0; h < 8; ++h)
                    xac[(((size_t)tc * B_ + b) * NH_ + h) * C_ + c] = p[h];
            }
        }
    }
}

// ---------------------------------------------------------------------------
// K5a: attn = e * fact.  grid (16 tc, 16 b) x 256 thr.
// fact computed redundantly per block from ms (trivial).
// ---------------------------------------------------------------------------
__global__ __launch_bounds__(256) void k5a_attn(const float* __restrict__ e,
                                                const float* __restrict__ ms,
                                                float* __restrict__ attn)
{
    int tc = blockIdx.x, b = blockIdx.y, tid = threadIdx.x;
    __shared__ float facts[8];
    if (tid < 8) {
        const float* mp = ms + ((size_t)(b * NH_ + tid)) * 32;
        float M = -1e30f;
        #pragma unroll
        for (int ck = 0; ck < 16; ++ck) M = fmaxf(M, mp[ck * 2]);
        float Z = 0.f;
        #pragma unroll
        for (int ck = 0; ck < 16; ++ck) Z += mp[ck * 2 + 1] * expf(mp[ck * 2] - M);
        facts[tid] = expf(mp[tc * 2] - M) / Z;
    }
    __syncthreads();
    #pragma unroll
    for (int idx = tid; idx < 512; idx += 256) {
        int h = idx >> 6, tq = idx & 63;
        const float4* ep = reinterpret_cast<const float4*>(
            e + ((size_t)(b * NH_ + h)) * T_ + tc * 256);
        float4* ap = reinterpret_cast<float4*>(
            attn + ((size_t)(b * NH_ + h)) * T_ + tc * 256);
        float f = facts[h];
        float4 a = ep[tq];
        a.x *= f; a.y *= f; a.z *= f; a.w *= f;
        ap[tq] = a;
    }
}

// ---------------------------------------------------------------------------
// K5b: xa = sum_ck xac*fact; z = (xa@v_w+v_b)@o_w+o_b; gz = g*sigmoid-gate.
// grid B_ x 1024 thr, 4-way split-K GEMMs.
// ---------------------------------------------------------------------------
__global__ __launch_bounds__(1024) void k5b_gz(const float* __restrict__ ms,
                                               const float* __restrict__ xac,
                                               const float* __restrict__ v_w,
                                               const float* __restrict__ v_b,
                                               const float* __restrict__ o_w,
                                               const float* __restrict__ o_b,
                                               const float* __restrict__ g,
                                               float* __restrict__ gz)
{
    int b = blockIdx.x, tid = threadIdx.x;
    __shared__ float fact[8][16];
    __shared__ float xaL[2048];      // [h][c]
    __shared__ float part[4][256];
    __shared__ float zp[256];
    __shared__ float Ms[8], iZs[8];

    if (tid < 8) {
        const float* mp = ms + ((size_t)(b * NH_ + tid)) * 32;
        float M = -1e30f;
        #pragma unroll
        for (int ck = 0; ck < 16; ++ck) M = fmaxf(M, mp[ck * 2]);
        float Z = 0.f;
        #pragma unroll
        for (int ck = 0; ck < 16; ++ck) Z += mp[ck * 2 + 1] * expf(mp[ck * 2] - M);
        Ms[tid] = M; iZs[tid] = 1.0f / Z;
    }
    __syncthreads();
    if (tid < 128) {
        int h = tid >> 4, ck = tid & 15;
        fact[h][ck] = expf(ms[((size_t)(b * NH_ + h)) * 32 + ck * 2] - Ms[h]) * iZs[h];
    }
    __syncthreads();

    for (int idx = tid; idx < 2048; idx += 1024) {
        int h = idx >> 8, c = idx & 255;
        float s = 0.f;
        #pragma unroll
        for (int ck = 0; ck < 16; ++ck)
            s += xac[(((size_t)ck * B_ + b) * NH_ + h) * C_ + c] * fact[h][ck];
        xaL[idx] = s;
    }
    __syncthreads();

    {   // v GEMM: j = col, ks = K-slice (64 c each)
        int j = tid & 255, ks = tid >> 8;
        int h = j >> 5;
        float s = 0.f;
        #pragma unroll 8
        for (int c = ks * 64; c < ks * 64 + 64; ++c) s += xaL[h * 256 + c] * v_w[c * 256 + j];
        part[ks][j] = s;
    }
    __syncthreads();
    if (tid < 256)
        zp[tid] = part[0][tid] + part[1][tid] + part[2][tid] + part[3][tid] + v_b[tid];
    __syncthreads();
    {   // o GEMM
        int j = tid & 255, ks = tid >> 8;
        float s = 0.f;
        #pragma unroll 8
        for (int i = ks * 64; i < ks * 64 + 64; ++i) s += zp[i] * o_w[i * 256 + j];
        part[ks][j] = s;
    }
    __syncthreads();
    if (tid < 256) {
        float z = part[0][tid] + part[1][tid] + part[2][tid] + part[3][tid] + o_b[tid];
        gz[b * 256 + tid] = g[b * 256 + tid] * z;
    }
}

// ---------------------------------------------------------------------------
// K6: fused residual+gate+LayerNorm, register-resident, shfl-reduce.
// ---------------------------------------------------------------------------
__global__ __launch_bounds__(256) void k6_ln(const float* __restrict__ F_vis,
                                             const float* __restrict__ gz,
                                             const float* __restrict__ ln_g,
                                             const float* __restrict__ ln_b,
                                             float* __restrict__ out)
{
    int b  = blockIdx.y;
    int t0 = blockIdx.x * 32;
    int tid = threadIdx.x;
    int t4 = tid & 7;
    int cb = tid >> 3;

    __shared__ float gzs[256], lgs[256], lbs[256];
    __shared__ float4 redS[4][8], redQ[4][8];
    __shared__ float4 mu4s[8], rs4s[8];

    gzs[tid] = gz[b * C_ + tid];
    lgs[tid] = ln_g[tid];
    lbs[tid] = ln_b[tid];
    __syncthreads();

    const float* fvb = F_vis + (size_t)b * C_ * T_ + t0 + t4 * 4;
    float4 v[8];
    float4 s = make_float4(0.f, 0.f, 0.f, 0.f);
    float4 q = make_float4(0.f, 0.f, 0.f, 0.f);
    #pragma unroll
    for (int k = 0; k < 8; ++k) {
        int c = cb + k * 32;
        float4 x = *reinterpret_cast<const float4*>(&fvb[(size_t)c * T_]);
        float gc = gzs[c];
        x.x += gc; x.y += gc; x.z += gc; x.w += gc;
        v[k] = x;
        s.x += x.x; s.y += x.y; s.z += x.z; s.w += x.w;
        q.x += x.x * x.x; q.y += x.y * x.y; q.z += x.z * x.z; q.w += x.w * x.w;
    }
    #pragma unroll
    for (int o = 8; o <= 32; o <<= 1) {
        s.x += __shfl_xor(s.x, o); s.y += __shfl_xor(s.y, o);
        s.z += __shfl_xor(s.z, o); s.w += __shfl_xor(s.w, o);
        q.x += __shfl_xor(q.x, o); q.y += __shfl_xor(q.y, o);
        q.z += __shfl_xor(q.z, o); q.w += __shfl_xor(q.w, o);
    }
    int wid = tid >> 6;
    if ((tid & 63) < 8) { redS[wid][t4] = s; redQ[wid][t4] = q; }
    __syncthreads();
    if (tid < 8) {
        float4 S = redS[0][tid], Q = redQ[0][tid];
        #pragma unroll
        for (int w = 1; w < 4; ++w) {
            float4 a = redS[w][tid], c2 = redQ[w][tid];
            S.x += a.x; S.y += a.y; S.z += a.z; S.w += a.w;
            Q.x += c2.x; Q.y += c2.y; Q.z += c2.z; Q.w += c2.w;
        }
        float4 mu, rs;
        mu.x = S.x * (1.0f / C_); mu.y = S.y * (1.0f / C_);
        mu.z = S.z * (1.0f / C_); mu.w = S.w * (1.0f / C_);
        rs.x = rsqrtf(fmaxf(Q.x * (1.0f / C_) - mu.x * mu.x, 0.f) + 1e-5f);
        rs.y = rsqrtf(fmaxf(Q.y * (1.0f / C_) - mu.y * mu.y, 0.f) + 1e-5f);
        rs.z = rsqrtf(fmaxf(Q.z * (1.0f / C_) - mu.z * mu.z, 0.f) + 1e-5f);
        rs.w = rsqrtf(fmaxf(Q.w * (1.0f / C_) - mu.w * mu.w, 0.f) + 1e-5f);
        mu4s[tid] = mu; rs4s[tid] = rs;
    }
    __syncthreads();
    float4 mu = mu4s[t4], rs = rs4s[t4];
    float* ob = out + (size_t)b * C_ * T_ + t0 + t4 * 4;
    #pragma unroll
    for (int k = 0; k < 8; ++k) {
        int c = cb + k * 32;
        float lg = lgs[c], lb = lbs[c];
        float4 o;
        o.x = (v[k].x - mu.x) * rs.x * lg + lb;
        o.y = (v[k].y - mu.y) * rs.y * lg + lb;
        o.z = (v[k].z - mu.z) * rs.z * lg + lb;
        o.w = (v[k].w - mu.w) * rs.w * lg + lb;
        *reinterpret_cast<float4*>(&ob[(size_t)c * T_]) = o;
    }
}

// ---------------------------------------------------------------------------
extern "C" void kernel_launch(void* const* d_in, const int* in_sizes, int n_in,
                              void* d_out, int out_size, void* d_ws, size_t ws_size,
                              hipStream_t stream)
{
    const float* F_vis     = (const float*)d_in[0];
    const float* F_text    = (const float*)d_in[1];
    const float* F_unified = (const float*)d_in[2];
    const float* F_teacher = (const float*)d_in[3];
    const float* tp_w1 = (const float*)d_in[4];
    const float* tp_b1 = (const float*)d_in[5];
    const float* tp_w2 = (const float*)d_in[6];
    const float* tp_b2 = (const float*)d_in[7];
    const float* q_w   = (const float*)d_in[8];
    const float* q_b   = (const float*)d_in[9];
    const float* k_w   = (const float*)d_in[10];
    const float* k_b   = (const float*)d_in[11];
    const float* v_w   = (const float*)d_in[12];
    const float* v_b   = (const float*)d_in[13];
    const float* o_w   = (const float*)d_in[14];
    const float* o_b   = (const float*)d_in[15];
    const float* fa_w  = (const float*)d_in[16];
    const float* fa_b  = (const float*)d_in[17];
    const float* gp_w  = (const float*)d_in[18];
    const float* gp_b  = (const float*)d_in[19];
    const float* ln_g  = (const float*)d_in[20];
    const float* ln_b  = (const float*)d_in[21];

    float* ws  = (float*)d_ws;
    float* t1  = ws;                    // 4096
    float* tv  = ws + 4096;             // 4096
    float* kq  = ws + 8192;             // 32768
    float* qkb = ws + 40960;            // 128
    float* g   = ws + 41088;            // 4096
    float* gz  = ws + 45184;            // 4096
    float* e   = ws + 49280;            // 524288 (2 MiB)
    float* ms  = ws + 573568;           // 4096
    float* xac = ws + 577664;           // 524288 (2 MiB)

    float* out  = (float*)d_out;
    float* attn = out + (size_t)B_ * C_ * T_;    // output #1 region

    k_t1gate<<<16, 512, 0, stream>>>(F_text, F_unified, F_teacher,
                                     tp_w1, tp_b1, fa_w, fa_b, gp_w, gp_b,
                                     t1, g);
    gemm16<256, 0><<<16, 512, 0, stream>>>(t1, tp_w2, tp_b2, tv);
    k_qkq<<<NH_, 512, 0, stream>>>(tv, q_w, q_b, k_w, k_b, kq, qkb);

    k2_scores<<<dim3(16, B_), 512, 0, stream>>>(F_vis, kq, qkb, e, ms, xac);
    k5a_attn<<<dim3(16, B_), 256, 0, stream>>>(e, ms, attn);
    k5b_gz<<<B_, 1024, 0, stream>>>(ms, xac, v_w, v_b, o_w, o_b, g, gz);
    k6_ln<<<dim3(128, B_), 256, 0, stream>>>(F_vis, gz, ln_g, ln_b, out);
}